// Round 9
// baseline (1455.870 us; speedup 1.0000x reference)
//
#include <hip/hip_runtime.h>
#include <stdint.h>

#define NN 20000
#define NE 200000
#define NG 128
#define NJOBS 3125
#define SLOTS 1024
#define NBLK 512
#define NTHR 256
#define GT (NBLK * NTHR)

typedef __attribute__((ext_vector_type(8))) short short8;
typedef __attribute__((ext_vector_type(4))) float f32x4;
typedef __attribute__((ext_vector_type(8))) _Float16 half8;
typedef __attribute__((ext_vector_type(2))) _Float16 half2v;
typedef __attribute__((ext_vector_type(2))) __fp16   pk16;

static __device__ __forceinline__ float bf2f(short s) {
    union { unsigned int u; float f; } x;
    x.u = ((unsigned int)(unsigned short)s) << 16;
    return x.f;
}
static __device__ __forceinline__ unsigned short f2bf(float f) {
    unsigned int u = __builtin_bit_cast(unsigned int, f);
    u += 0x7fffu + ((u >> 16) & 1u);
    return (unsigned short)(u >> 16);
}
static __device__ __forceinline__ unsigned short f2h(float f) {
    _Float16 h = (_Float16)f;
    return __builtin_bit_cast(unsigned short, h);
}
static __device__ __forceinline__ int detect_isbf(const unsigned int* x) {
    unsigned int u = x[threadIdx.x & 63];
    unsigned int el = (u >> 7) & 0xffu;
    unsigned long long bm = __ballot((el >= 100u) && (el <= 140u));
    return __popcll(bm) > 32;
}

// ---- device-scope grid barrier: all NBLK blocks are co-resident (2/CU) ----
static __device__ __forceinline__ void gbar(int* bcnt, int* bgen) {
    __threadfence();                   // release: all threads' prior writes
    __syncthreads();
    if (threadIdx.x == 0) {
        int g = __hip_atomic_load(bgen, __ATOMIC_RELAXED, __HIP_MEMORY_SCOPE_AGENT);
        int a = __hip_atomic_fetch_add(bcnt, 1, __ATOMIC_ACQ_REL, __HIP_MEMORY_SCOPE_AGENT);
        if (a == NBLK - 1) {
            __hip_atomic_store(bcnt, 0, __ATOMIC_RELAXED, __HIP_MEMORY_SCOPE_AGENT);
            __hip_atomic_store(bgen, g + 1, __ATOMIC_RELEASE, __HIP_MEMORY_SCOPE_AGENT);
        } else {
            while (__hip_atomic_load(bgen, __ATOMIC_ACQUIRE, __HIP_MEMORY_SCOPE_AGENT) <= g)
                __builtin_amdgcn_s_sleep(1);
        }
    }
    __syncthreads();
    __threadfence();                   // acquire: subsequent reads see remote writes
}

struct Shm {
    union {
        struct { short w2t[32 * 552]; float h1s[4 * 64 * 20]; } edge;  // 55.8 KB
        struct { float wf[2048]; float bfs[32]; } emb;
        struct { float rf[1024]; float bfs[32]; } agg;
        struct { int s40[48]; int pair[512]; } scan;
    };
};

// ------------------------------------------------------------------ edge phase:
// msg = P @ W2' over sorted edges; this block's K-half in LDS (f16); h1 fp32 in
// per-wave LDS; f16 MFMA; fully software-pipelined inputs; plain packed stores.
__device__ __noinline__ void edge_phase(
    const float* __restrict__ h_in, const short* __restrict__ W2T,
    const short* __restrict__ w1pre, const float* __restrict__ b1pre,
    const int* __restrict__ src_s, const short* __restrict__ ea_s,
    unsigned int* __restrict__ msg_out, short* w2t, float* h1s, int khalf) {
    const int k0 = khalf ? 512 : 0;
    const int KS = khalf ? 552 : 520;
    const int KLEN = khalf ? 544 : 512;

    {   // stage W2T half -> LDS
        int cpr = KLEN >> 3, chunks = 32 * cpr;
        for (int idx = threadIdx.x; idx < chunks; idx += NTHR) {
            int o = idx / cpr, t8 = idx - o * cpr;
            *(short8*)&w2t[o * KS + (t8 << 3)] =
                *(const short8*)&W2T[o * 1056 + k0 + (t8 << 3)];
        }
    }
    __syncthreads();

    const int lane = threadIdx.x & 63;
    const int wid  = threadIdx.x >> 6;
    const int m    = lane & 15;
    const int quad = lane >> 4;
    float* h1w = h1s + wid * (64 * 20);

    half8 w1frag = (half8)0;
    if (quad < 2) {
        int c = m + (khalf << 4);
        w1frag = __builtin_bit_cast(half8, *(const short8*)&w1pre[c * 16 + ((quad & 1) << 3)]);
    }
    const float b1v = b1pre[m + (khalf << 4)];
    const f32x4 zero4 = {0.f, 0.f, 0.f, 0.f};

    int j = (blockIdx.x >> 1) * 4 + wid;  // slot 0..1023 within this half

    half8 eafc[4];
    f32x4 hs[4][2];
    int srcn[4];
    {
        const int e0 = j << 6;
        int s0[4];
#pragma unroll
        for (int mt = 0; mt < 4; ++mt) {
            eafc[mt] = __builtin_bit_cast(half8,
                *(const short8*)&ea_s[(size_t)(e0 + mt * 16 + m) * 16 + ((quad & 1) << 3)]);
            s0[mt] = src_s[e0 + mt * 16 + m];
        }
#pragma unroll
        for (int mt = 0; mt < 4; ++mt) {
            const float* hr = h_in + (size_t)s0[mt] * 32 + (quad << 3);
            hs[mt][0] = *(const f32x4*)hr;
            hs[mt][1] = *(const f32x4*)(hr + 4);
        }
        const int en = (j + SLOTS) << 6;
#pragma unroll
        for (int mt = 0; mt < 4; ++mt) srcn[mt] = src_s[en + mt * 16 + m];
    }

    while (j < NJOBS) {
        const int e0 = j << 6;
        const int jn = j + SLOTS;

        // phase 1: h1 = relu(ea@w1+b1) -> fp32 LDS
#pragma unroll
        for (int mt = 0; mt < 4; ++mt) {
            half8 eaq = (quad < 2) ? eafc[mt] : (half8)0;
            f32x4 hacc = __builtin_amdgcn_mfma_f32_16x16x32_f16(eaq, w1frag, zero4, 0, 0, 0);
#pragma unroll
            for (int r = 0; r < 4; ++r) {
                float v = hacc[r] + b1v;
                v = v > 0.f ? v : 0.f;
                h1w[(mt * 16 + quad * 4 + r) * 20 + m] = v;
            }
        }
        if (khalf) h1w[lane * 20 + 16] = 1.0f;
        __asm volatile("s_waitcnt lgkmcnt(0)" ::: "memory");

        if (jn < NJOBS) {
            const int en = jn << 6;
#pragma unroll
            for (int mt = 0; mt < 4; ++mt)
                eafc[mt] = __builtin_bit_cast(half8,
                    *(const short8*)&ea_s[(size_t)(en + mt * 16 + m) * 16 + ((quad & 1) << 3)]);
        }

        // phase 2: K loop, weights from LDS
        f32x4 acc0[4], acc1[4];
#pragma unroll
        for (int mt = 0; mt < 4; ++mt) { acc0[mt] = zero4; acc1[mt] = zero4; }

#pragma unroll
        for (int c = 0; c < 4; ++c) {
            f32x4 h4[4];
#pragma unroll
            for (int mt = 0; mt < 4; ++mt)
                h4[mt] = *(const f32x4*)&h1w[(mt * 16 + m) * 20 + (c << 2)];
#pragma unroll
            for (int u = 0; u < 4; ++u) {
                const int s = (c << 2) + u;
                half8 bf0 = __builtin_bit_cast(half8,
                    *(const short8*)&w2t[m * KS + (s << 5) + (quad << 3)]);
                half8 bf1 = __builtin_bit_cast(half8,
                    *(const short8*)&w2t[(m + 16) * KS + (s << 5) + (quad << 3)]);
#pragma unroll
                for (int mt = 0; mt < 4; ++mt) {
                    float sc = h4[mt][u];
                    union { pk16 h2[4]; half8 v; } a;
#pragma unroll
                    for (int p = 0; p < 4; ++p) {
                        f32x4 hv = hs[mt][p >> 1];
                        a.h2[p] = __builtin_amdgcn_cvt_pkrtz(sc * hv[(p & 1) * 2],
                                                             sc * hv[(p & 1) * 2 + 1]);
                    }
                    acc0[mt] = __builtin_amdgcn_mfma_f32_16x16x32_f16(a.v, bf0, acc0[mt], 0, 0, 0);
                    acc1[mt] = __builtin_amdgcn_mfma_f32_16x16x32_f16(a.v, bf1, acc1[mt], 0, 0, 0);
                }
            }
        }
        if (khalf) {  // tail s=16 (bias rows)
            half8 bf0 = __builtin_bit_cast(half8,
                *(const short8*)&w2t[m * KS + (16 << 5) + (quad << 3)]);
            half8 bf1 = __builtin_bit_cast(half8,
                *(const short8*)&w2t[(m + 16) * KS + (16 << 5) + (quad << 3)]);
#pragma unroll
            for (int mt = 0; mt < 4; ++mt) {
                float sc = h1w[(mt * 16 + m) * 20 + 16];
                union { pk16 h2[4]; half8 v; } a;
#pragma unroll
                for (int p = 0; p < 4; ++p) {
                    f32x4 hv = hs[mt][p >> 1];
                    a.h2[p] = __builtin_amdgcn_cvt_pkrtz(sc * hv[(p & 1) * 2],
                                                         sc * hv[(p & 1) * 2 + 1]);
                }
                acc0[mt] = __builtin_amdgcn_mfma_f32_16x16x32_f16(a.v, bf0, acc0[mt], 0, 0, 0);
                acc1[mt] = __builtin_amdgcn_mfma_f32_16x16x32_f16(a.v, bf1, acc1[mt], 0, 0, 0);
            }
        }

        if (jn < NJOBS) {
#pragma unroll
            for (int mt = 0; mt < 4; ++mt) {
                const float* hr = h_in + (size_t)srcn[mt] * 32 + (quad << 3);
                hs[mt][0] = *(const f32x4*)hr;
                hs[mt][1] = *(const f32x4*)(hr + 4);
            }
            const int jn2 = jn + SLOTS;
            if (jn2 < NJOBS) {
                const int en2 = jn2 << 6;
#pragma unroll
                for (int mt = 0; mt < 4; ++mt) srcn[mt] = src_s[en2 + mt * 16 + m];
            }
        }

#pragma unroll
        for (int mt = 0; mt < 4; ++mt) {
#pragma unroll
            for (int r = 0; r < 4; ++r) {
                pk16 pk = __builtin_amdgcn_cvt_pkrtz(acc0[mt][r], acc1[mt][r]);
                msg_out[(size_t)(e0 + mt * 16 + quad * 4 + r) * 16 + m] =
                    __builtin_bit_cast(unsigned int, pk);
            }
        }
        j = jn;
    }
}

// ------------------------------------------------------------------ agg phase
__device__ __noinline__ void agg_phase(
    const unsigned int* __restrict__ msgA, const unsigned int* __restrict__ msgB,
    const int* __restrict__ row_ptr, const float* __restrict__ h_prev,
    const void* root, const void* bias, int isbf, const int* __restrict__ batch,
    int mode, float* __restrict__ h1b, void* __restrict__ out, float* pooled,
    float* rf, float* bfs) {
    for (int i = threadIdx.x; i < 1024; i += NTHR)
        rf[i] = isbf ? bf2f(((const short*)root)[i]) : ((const float*)root)[i];
    if (threadIdx.x < 32)
        bfs[threadIdx.x] = isbf ? bf2f(((const short*)bias)[threadIdx.x])
                                : ((const float*)bias)[threadIdx.x];
    __syncthreads();
    const int tid = blockIdx.x * NTHR + threadIdx.x;
    for (int t = tid; t < NN * 32; t += GT) {
        int d = t >> 5, c = t & 31;
        const float* hr = h_prev + (size_t)d * 32;
        float acc = bfs[c];
#pragma unroll
        for (int q = 0; q < 32; ++q) acc += hr[q] * rf[q * 32 + c];
        const int b0 = row_ptr[d], b1 = row_ptr[d + 1];
        const int ci = c & 15, hi = c >> 4;
        float s = 0.f;
        for (int e = b0; e < b1; ++e) {
            half2v ha = __builtin_bit_cast(half2v, msgA[(size_t)e * 16 + ci]);
            half2v hb = __builtin_bit_cast(half2v, msgB[(size_t)e * 16 + ci]);
            s += (float)ha[hi] + (float)hb[hi];
        }
        float v = acc + s;
        v = v > 0.f ? v : 0.01f * v;
        if (mode == 0) {
            h1b[t] = v;
        } else {
            if (isbf) ((short*)out)[4096 + t] = (short)f2bf(v);
            else      ((float*)out)[4096 + t] = v;
            atomicAdd(&pooled[batch[d] * 32 + c], v);
        }
    }
    __syncthreads();
}

// ------------------------------------------------------------------ the kernel
__global__ __launch_bounds__(NTHR, 2) void k_all(
    const void* x, const int* __restrict__ eidx, const void* ea,
    const int* __restrict__ batch,
    const void* nw, const void* nb,
    const void* e1w1, const void* e1b1, const void* e1w2, const void* e1b2,
    const void* root1, const void* bias1,
    const void* e2w1, const void* e2b1, const void* e2w2, const void* e2b2,
    const void* root2, const void* bias2,
    const void* fcw, const void* fcb,
    float* h0, float* h1b, unsigned int* msgA, unsigned int* msgB,
    short* ea_s, int* src_s, short* W2T1, short* W2T2,
    short* w1t_ws, float* b1f_ws, int* row_ptr, int* ptr_wk,
    int* cnt, int* bsum, int* bar, float* pooled, void* out) {
    __shared__ Shm shm;
    const int isbf = detect_isbf((const unsigned int*)x);
    const int tid = blockIdx.x * NTHR + threadIdx.x;
    const int* src = eidx;
    const int* dst = eidx + NE;
    int* bcnt = bar;
    int* bgen = bar + 1;

    // ===== P0: W2T (f16) + w1t/b1f + node embed + dst histogram =====
    for (int t = tid; t < 2 * 32 * 1056; t += GT) {
        int layer = t / (32 * 1056);
        int r = t - layer * (32 * 1056);
        int o = r / 1056, kp = r - o * 1056;
        const void* w2 = layer ? e2w2 : e1w2;
        const void* b2 = layer ? e2b2 : e1b2;
        int idx; const void* sp;
        if (kp < 1024) { int kk = kp >> 5, i = kp & 31; idx = kk * 1024 + i * 32 + o; sp = w2; }
        else           { int i = kp - 1024;             idx = i * 32 + o;             sp = b2; }
        float v = isbf ? bf2f(((const short*)sp)[idx]) : ((const float*)sp)[idx];
        (layer ? W2T2 : W2T1)[o * 1056 + kp] = (short)f2h(v);
    }
    if (tid < 1024) {
        int layer = tid >> 9, jj = tid & 511, c = jj >> 4, q = jj & 15;
        const void* w1p = layer ? e2w1 : e1w1;
        float v = isbf ? bf2f(((const short*)w1p)[q * 32 + c])
                       : ((const float*)w1p)[q * 32 + c];
        w1t_ws[tid] = (short)f2h(v);
    }
    if (tid < 64) {
        int layer = tid >> 5, c = tid & 31;
        const void* b1p = layer ? e2b1 : e1b1;
        b1f_ws[tid] = isbf ? bf2f(((const short*)b1p)[c]) : ((const float*)b1p)[c];
    }
    {   // node embed (wf staged in LDS per block)
        for (int i = threadIdx.x; i < 2048; i += NTHR)
            shm.emb.wf[i] = isbf ? bf2f(((const short*)nw)[i]) : ((const float*)nw)[i];
        if (threadIdx.x < 32)
            shm.emb.bfs[threadIdx.x] = isbf ? bf2f(((const short*)nb)[threadIdx.x])
                                            : ((const float*)nb)[threadIdx.x];
        __syncthreads();
        for (int t = tid; t < NN * 32; t += GT) {
            int v = t >> 5, c = t & 31;
            float acc = shm.emb.bfs[c];
            if (isbf) {
                const short* xr = (const short*)x + v * 64;
#pragma unroll
                for (int q = 0; q < 64; ++q) acc += bf2f(xr[q]) * shm.emb.wf[q * 32 + c];
            } else {
                const float* xr = (const float*)x + v * 64;
#pragma unroll
                for (int q = 0; q < 64; ++q) acc += xr[q] * shm.emb.wf[q * 32 + c];
            }
            h0[t] = acc > 0.f ? acc : 0.01f * acc;
        }
    }
    for (int e = tid; e < NE; e += GT) atomicAdd(&cnt[dst[e]], 1);
    gbar(bcnt, bgen);

    // ===== P1a: per-block chunk scan (40 nodes/block) =====
    {
        int base = blockIdx.x * 40;
        if (threadIdx.x < 40) {
            int idx = base + threadIdx.x;
            shm.scan.s40[threadIdx.x] = (idx < NN) ? cnt[idx] : 0;
        }
        __syncthreads();
        if (threadIdx.x == 0) {
            int run = 0;
#pragma unroll
            for (int i = 0; i < 40; ++i) { int tmp = shm.scan.s40[i]; shm.scan.s40[i] = run; run += tmp; }
            shm.scan.s40[40] = run;
            bsum[blockIdx.x] = run;
        }
        __syncthreads();
        if (threadIdx.x < 40) {
            int idx = base + threadIdx.x;
            if (idx < NN) row_ptr[idx] = shm.scan.s40[threadIdx.x];
        }
    }
    gbar(bcnt, bgen);

    // ===== P1b: block 0 scans the 512 block sums =====
    if (blockIdx.x == 0) {
        int t = threadIdx.x;
        int a0 = bsum[2 * t], a1 = bsum[2 * t + 1];
        shm.scan.pair[t] = a0 + a1;
        __syncthreads();
        for (int off = 1; off < 256; off <<= 1) {
            int v = (t >= off) ? shm.scan.pair[t - off] : 0;
            __syncthreads();
            shm.scan.pair[t] += v;
            __syncthreads();
        }
        int excl = shm.scan.pair[t] - (a0 + a1);
        bsum[2 * t] = excl;
        bsum[2 * t + 1] = excl + a0;
    }
    gbar(bcnt, bgen);

    // ===== P1c: add block offsets -> row_ptr, ptr_wk =====
    if (threadIdx.x < 40) {
        int idx = blockIdx.x * 40 + threadIdx.x;
        if (idx < NN) {
            int v = row_ptr[idx] + bsum[blockIdx.x];
            row_ptr[idx] = v;
            ptr_wk[idx] = v;
        }
    }
    if (tid == 0) row_ptr[NN] = NE;
    gbar(bcnt, bgen);

    // ===== P2: counting-sort scatter (src_s + f16 ea_s) =====
    for (int e = tid; e < NE; e += GT) {
        int d = dst[e];
        int p = atomicAdd(&ptr_wk[d], 1);
        src_s[p] = src[e];
        union { unsigned short us[16]; short8 v[2]; } o16;
        if (isbf) {
            const short* q = (const short*)ea + (size_t)e * 16;
#pragma unroll
            for (int i = 0; i < 16; ++i) o16.us[i] = f2h(bf2f(q[i]));
        } else {
            const float* q = (const float*)ea + (size_t)e * 16;
#pragma unroll
            for (int i = 0; i < 16; ++i) o16.us[i] = f2h(q[i]);
        }
        *(short8*)&ea_s[(size_t)p * 16] = o16.v[0];
        *(short8*)&ea_s[(size_t)p * 16 + 8] = o16.v[1];
    }
    gbar(bcnt, bgen);

    // ===== P3: edge GEMM layer 1 =====
    {
        int khalf = blockIdx.x & 1;
        edge_phase(h0, W2T1, w1t_ws, b1f_ws, src_s, ea_s,
                   khalf ? msgB : msgA, shm.edge.w2t, shm.edge.h1s, khalf);
    }
    gbar(bcnt, bgen);

    // ===== P4: aggregate layer 1 -> h1b =====
    agg_phase(msgA, msgB, row_ptr, h0, root1, bias1, isbf, batch, 0,
              h1b, out, pooled, shm.agg.rf, shm.agg.bfs);
    gbar(bcnt, bgen);

    // ===== P5: edge GEMM layer 2 =====
    {
        int khalf = blockIdx.x & 1;
        edge_phase(h1b, W2T2, w1t_ws + 512, b1f_ws + 32, src_s, ea_s,
                   khalf ? msgB : msgA, shm.edge.w2t, shm.edge.h1s, khalf);
    }
    gbar(bcnt, bgen);

    // ===== P6: aggregate layer 2 -> atom_embs + pooled =====
    agg_phase(msgA, msgB, row_ptr, h1b, root2, bias2, isbf, batch, 1,
              h1b, out, pooled, shm.agg.rf, shm.agg.bfs);
    gbar(bcnt, bgen);

    // ===== P7: graph head (first 128 blocks, wave 0, lanes 0..31) =====
    if (blockIdx.x < NG && threadIdx.x < 32) {
        int g = blockIdx.x, t = threadIdx.x;
        float p = pooled[g * 32 + t];
        float sq = p * p;
#pragma unroll
        for (int o = 16; o > 0; o >>= 1) sq += __shfl_xor(sq, o, 64);
        float pnorm = p / fmaxf(sqrtf(sq), 1e-12f);
        float acc = isbf ? bf2f(((const short*)fcb)[t]) : ((const float*)fcb)[t];
#pragma unroll
        for (int q = 0; q < 32; ++q) {
            float pq = __shfl(pnorm, q, 64);
            float wv = isbf ? bf2f(((const short*)fcw)[q * 32 + t])
                            : ((const float*)fcw)[q * 32 + t];
            acc += pq * wv;
        }
        if (isbf) ((short*)out)[g * 32 + t] = (short)f2bf(acc);
        else      ((float*)out)[g * 32 + t] = acc;
    }
}

extern "C" void kernel_launch(void* const* d_in, const int* in_sizes, int n_in,
                              void* d_out, int out_size, void* d_ws, size_t ws_size,
                              hipStream_t stream) {
    (void)in_sizes; (void)n_in; (void)out_size; (void)ws_size;
    const void* x     = d_in[0];
    const int*  eidx  = (const int*)d_in[1];
    const void* ea    = d_in[2];
    const int*  batch = (const int*)d_in[3];
    const void* nfcw  = d_in[5];
    const void* nfcb  = d_in[6];
    const void* e1w1  = d_in[7];
    const void* e1b1  = d_in[8];
    const void* e1w2  = d_in[9];
    const void* e1b2  = d_in[10];
    const void* root1 = d_in[11];
    const void* bias1 = d_in[12];
    const void* e2w1  = d_in[13];
    const void* e2b1  = d_in[14];
    const void* e2w2  = d_in[15];
    const void* e2b2  = d_in[16];
    const void* root2 = d_in[17];
    const void* bias2 = d_in[18];
    const void* fcw   = d_in[19];
    const void* fcb   = d_in[20];

    char* ws = (char*)d_ws;
    float* h0     = (float*)ws;        ws += (size_t)NN * 32 * 4;
    float* h1b    = (float*)ws;        ws += (size_t)NN * 32 * 4;
    unsigned int* msgA = (unsigned int*)ws; ws += (size_t)NE * 16 * 4;
    unsigned int* msgB = (unsigned int*)ws; ws += (size_t)NE * 16 * 4;
    short* ea_s   = (short*)ws;        ws += (size_t)NE * 16 * 2;
    int*   src_s  = (int*)ws;          ws += (size_t)NE * 4;
    short* W2T1   = (short*)ws;        ws += 32 * 1056 * 2;
    short* W2T2   = (short*)ws;        ws += 32 * 1056 * 2;
    short* w1t_ws = (short*)ws;        ws += 1024 * 2;
    float* b1f_ws = (float*)ws;        ws += 64 * 4;
    int*   row_ptr= (int*)ws;          ws += (size_t)(NN + 8) * 4;
    int*   ptr_wk = (int*)ws;          ws += (size_t)NN * 4;
    // ---- contiguous zero region: cnt | bsum | bar | pooled ----
    char*  zbase  = ws;
    int*   cnt    = (int*)ws;          ws += (size_t)NN * 4;
    int*   bsum   = (int*)ws;          ws += (size_t)NBLK * 4;
    int*   bar    = (int*)ws;          ws += 4 * 4;
    float* pooled = (float*)ws;        ws += (size_t)NG * 32 * 4;
    size_t zsize  = (size_t)(ws - zbase);

    hipMemsetAsync(zbase, 0, zsize, stream);
    k_all<<<NBLK, NTHR, 0, stream>>>(
        x, eidx, ea, batch, nfcw, nfcb,
        e1w1, e1b1, e1w2, e1b2, root1, bias1,
        e2w1, e2b1, e2w2, e2b2, root2, bias2,
        fcw, fcb,
        h0, h1b, msgA, msgB, ea_s, src_s, W2T1, W2T2,
        w1t_ws, b1f_ws, row_ptr, ptr_wk, cnt, bsum, bar, pooled, d_out);
}